// Round 10
// baseline (404.610 us; speedup 1.0000x reference)
//
#include <hip/hip_runtime.h>

#define D_IN 256
#define D_HALF 128

typedef __attribute__((ext_vector_type(8))) short short8;
typedef __attribute__((ext_vector_type(4))) float float4v;

__device__ __forceinline__ unsigned short f2bf(float f) {
    union { float f; unsigned u; } v; v.f = f;
    unsigned r = v.u + 0x7FFF + ((v.u >> 16) & 1);   // RNE
    return (unsigned short)(r >> 16);
}
__device__ __forceinline__ float bflo(unsigned u) { union { unsigned u; float f; } v; v.u = u << 16; return v.f; }
__device__ __forceinline__ float bfhi(unsigned u) { union { unsigned u; float f; } v; v.u = u & 0xffff0000u; return v.f; }

__device__ __forceinline__ void async16(const void* g, void* l) {
    __builtin_amdgcn_global_load_lds(
        (const __attribute__((address_space(1))) unsigned int*)g,
        (__attribute__((address_space(3))) unsigned int*)l, 16, 0, 0);
}

// ---------------- CSR build ----------------
// Fixed-capacity bucket sort. Bucket = 512 consecutive csr slots.
// Item packed in u32: (slot_local << 23) | nbr   (needs N < 2^23).

#define S_SH 9               // 512 csr slots per bucket
#define NBK_MAX 512          // max buckets (M <= 512*512 = 262144)
#define CAP 12288            // items per bucket capacity (mean 8184, sigma ~90)
#define EPB 4096             // edges per p1 block (16 per thread @ 256 thr)

// Fat kernel: blocks [0, nP1) run the p1 partition pass; blocks [nP1, ...)
// run the independent x/W bf16 cast and fill idle CUs.
// p1 staging writes are COALESCED via LDS reorder: items are scattered into
// a bucket-grouped LDS buffer (rank known from the histogram pass), then
// streamed out so consecutive threads write consecutive addresses inside
// each bucket run (~21 items). Previously the per-lane scatter fragmented
// every store into ~64 line transactions (the R2 partition_kernel symptom:
// 132 MB WRITE for a 26 MB payload).
__global__ void p1_cast_kernel(const int* __restrict__ col, const int* __restrict__ row,
                               int* __restrict__ gcnt, unsigned* __restrict__ staging,
                               int N, int E, int nP1,
                               const float* __restrict__ x, const float* __restrict__ Wf,
                               const float* __restrict__ Wb, unsigned short* __restrict__ xb,
                               unsigned short* __restrict__ wcat, int n4) {
    __shared__ int hist[NBK_MAX];
    __shared__ int base_[NBK_MAX];
    __shared__ int lstart[NBK_MAX];
    __shared__ int s[256];
    __shared__ unsigned lbuf[2 * EPB];
    __shared__ unsigned short lbk[2 * EPB];
    const int tid = threadIdx.x;

    if (blockIdx.x >= nP1) {
        // ---- cast branch (no barriers) ----
        int i = (blockIdx.x - nP1) * 256 + tid;
        const int w4 = (2 * D_HALF * D_IN) / 4;
        if (i < n4) {
            float4 v = ((const float4*)x)[i];
            ushort4 o = { f2bf(v.x), f2bf(v.y), f2bf(v.z), f2bf(v.w) };
            ((ushort4*)xb)[i] = o;
        } else if (i < n4 + w4) {
            int j = i - n4;
            int elem = j * 4;
            const float* src = (elem < D_HALF * D_IN) ? (Wf + elem) : (Wb + (elem - D_HALF * D_IN));
            float4 v = *(const float4*)src;
            ushort4 o = { f2bf(v.x), f2bf(v.y), f2bf(v.z), f2bf(v.w) };
            ((ushort4*)wcat)[j] = o;
        }
        return;
    }

    // ---- phase A: stream edges once (held in registers); LDS-atomic
    // return value IS the within-block rank for that bucket. ----
    hist[tid] = 0; hist[tid + 256] = 0;
    __syncthreads();

    int ce[16], re[16], rf_[16], rb_[16];
    const int e0 = blockIdx.x * EPB;
    #pragma unroll
    for (int j = 0; j < 16; ++j) {
        int e = e0 + j * 256 + tid;
        if (e < E) {
            ce[j] = col[e];
            re[j] = row[e];
            rf_[j] = atomicAdd(&hist[ce[j] >> S_SH], 1);
            rb_[j] = atomicAdd(&hist[(N + re[j]) >> S_SH], 1);
        } else {
            ce[j] = -1; re[j] = 0; rf_[j] = 0; rb_[j] = 0;
        }
    }
    __syncthreads();

    // ---- phase B: claim global runs; phase C: local pair-scan -> lstart ----
    int c0 = hist[2 * tid], c1 = hist[2 * tid + 1];
    if (c0) base_[2 * tid]     = (2 * tid) * CAP     + atomicAdd(&gcnt[2 * tid], c0);
    if (c1) base_[2 * tid + 1] = (2 * tid + 1) * CAP + atomicAdd(&gcnt[2 * tid + 1], c1);
    int pair = c0 + c1;
    s[tid] = pair;
    __syncthreads();
    for (int d = 1; d < 256; d <<= 1) {
        int t = (tid >= d) ? s[tid - d] : 0;
        __syncthreads();
        s[tid] += t;
        __syncthreads();
    }
    int excl = s[tid] - pair;
    lstart[2 * tid] = excl;
    lstart[2 * tid + 1] = excl + c0;
    __syncthreads();
    const int total = s[255];

    // ---- phase D: scatter items into bucket-grouped LDS buffer ----
    #pragma unroll
    for (int j = 0; j < 16; ++j) {
        if (ce[j] >= 0) {
            int c = ce[j], r = re[j];
            int bf = c >> S_SH;
            int pf = lstart[bf] + rf_[j];
            lbuf[pf] = ((unsigned)(c & 511) << 23) | (unsigned)r;
            lbk[pf] = (unsigned short)bf;
            int sb = N + r;
            int bb = sb >> S_SH;
            int pb = lstart[bb] + rb_[j];
            lbuf[pb] = ((unsigned)(sb & 511) << 23) | (unsigned)c;
            lbk[pb] = (unsigned short)bb;
        }
    }
    __syncthreads();

    // ---- phase E: coalesced streaming write of bucket runs ----
    for (int i = tid; i < total; i += 256) {
        int bk = lbk[i];
        staging[(size_t)base_[bk] + (i - lstart[bk])] = lbuf[i];
    }
}

// One block per bucket. Inlined: (a) 512-wide LDS scan of gcnt -> this
// bucket's global base; (b) per-slot hist + pair scan -> cnt/offs AND
// inv_in/inv_out written directly; (c) rank+scatter into LDS, coalesced
// contiguous adj write.
__global__ void bsort_kernel(const unsigned* __restrict__ staging, const int* __restrict__ gcnt,
                             int* __restrict__ cnt, int* __restrict__ offs,
                             float* __restrict__ inv_in, float* __restrict__ inv_out,
                             int* __restrict__ adj, int N, int M) {
    __shared__ int lcnt[NBK_MAX];
    __shared__ int s[256];
    __shared__ int lbuf[CAP];
    __shared__ int bc[2];            // [0]=base, [1]=count broadcast
    const int tid = threadIdx.x;
    const int b = blockIdx.x;
    const int s0 = b << S_SH;

    // (a) bucket-base scan: prefix over gcnt[0..512)
    int g0 = gcnt[2 * tid], g1 = gcnt[2 * tid + 1];
    int pairB = g0 + g1;
    s[tid] = pairB;
    __syncthreads();
    for (int d = 1; d < 256; d <<= 1) {
        int t = (tid >= d) ? s[tid - d] : 0;
        __syncthreads();
        s[tid] += t;
        __syncthreads();
    }
    if (tid == (b >> 1)) {
        int excl = s[tid] - pairB;               // prefix before bucket 2*tid
        bc[0] = excl + ((b & 1) ? g0 : 0);
        bc[1] = (b & 1) ? g1 : g0;
    }
    lcnt[tid] = 0; lcnt[tid + 256] = 0;
    __syncthreads();

    const int base = bc[0];
    const int count = bc[1];
    const unsigned* __restrict__ st = staging + (size_t)b * CAP;

    // (b) per-slot histogram
    for (int i = tid; i < count; i += 256)
        atomicAdd(&lcnt[st[i] >> 23], 1);
    __syncthreads();

    int v0 = lcnt[2 * tid], v1 = lcnt[2 * tid + 1];
    int pair = v0 + v1;
    s[tid] = pair;
    __syncthreads();
    for (int d = 1; d < 256; d <<= 1) {
        int t = (tid >= d) ? s[tid - d] : 0;
        __syncthreads();
        s[tid] += t;
        __syncthreads();
    }
    int excl = s[tid] - pair;

    int gs0 = s0 + 2 * tid;
    if (gs0 < M) {
        cnt[gs0] = v0;  offs[gs0] = base + excl;
        if (gs0 < N) inv_in[gs0] = rsqrtf((float)(v0 + 1));
        else         inv_out[gs0 - N] = rsqrtf((float)(v0 + 1));
    }
    if (gs0 + 1 < M) {
        cnt[gs0 + 1] = v1;  offs[gs0 + 1] = base + excl + v0;
        if (gs0 + 1 < N) inv_in[gs0 + 1] = rsqrtf((float)(v1 + 1));
        else             inv_out[gs0 + 1 - N] = rsqrtf((float)(v1 + 1));
    }

    // reuse lcnt as running positions
    lcnt[2 * tid] = excl;
    lcnt[2 * tid + 1] = excl + v0;
    __syncthreads();

    // (c) rank + LDS scatter, then coalesced write
    for (int i = tid; i < count; i += 256) {
        unsigned it = st[i];
        int sl = it >> 23;
        int p = atomicAdd(&lcnt[sl], 1);
        lbuf[p] = (int)(it & 0x7fffffu);
    }
    __syncthreads();
    for (int i = tid; i < count; i += 256)
        adj[base + i] = lbuf[i];
}

// ---------------- bf16 MFMA GEMM with pre-scaled epilogue ----------------
// zb[m][n] = f2bf( (sum_k xb[m][k]*wcat[n][k]) * s[m] )
// s[m] = inv_out[m] for forward half (blockIdx.y==0), inv_in[m] for backward.

#define BM 128
#define BN 128
#define BK 32

__global__ void gemm_mfma_kernel(const unsigned short* __restrict__ xb,
                                 const unsigned short* __restrict__ wcat,
                                 const float* __restrict__ inv_in,
                                 const float* __restrict__ inv_out,
                                 unsigned short* __restrict__ zb, int N) {
    __shared__ __align__(16) unsigned short As[BM * BK];
    __shared__ __align__(16) unsigned short Bs[BN * BK];
    const int tid = threadIdx.x;
    const int wave = tid >> 6;
    const int lane = tid & 63;
    const int bm = blockIdx.x * BM;
    const int bn = blockIdx.y * BN;
    const int warpM = wave >> 1;   // 0..1
    const int warpN = wave & 1;    // 0..1
    const int l15 = lane & 15;
    const int quad = lane >> 4;

    float4v acc[4][4];
    #pragma unroll
    for (int i = 0; i < 4; ++i)
        #pragma unroll
        for (int j = 0; j < 4; ++j)
            acc[i][j] = (float4v){0.f, 0.f, 0.f, 0.f};

    for (int kt = 0; kt < D_IN / BK; ++kt) {
        #pragma unroll
        for (int iss = 0; iss < 2; ++iss) {
            const int pbase = iss * 256 + wave * 64;
            const int p = pbase + lane;
            const int m = p >> 2;
            const int g = (p & 3) ^ ((m >> 1) & 3);
            int gm = bm + m; if (gm >= N) gm = N - 1;
            async16(xb + (size_t)gm * D_IN + kt * BK + g * 8, &As[pbase * 8]);
            async16(wcat + (size_t)(bn + m) * D_IN + kt * BK + g * 8, &Bs[pbase * 8]);
        }
        __syncthreads();

        short8 af[4], bfr[4];
        #pragma unroll
        for (int mi = 0; mi < 4; ++mi) {
            int m = warpM * 64 + mi * 16 + l15;
            af[mi] = *(const short8*)&As[m * BK + (quad ^ ((m >> 1) & 3)) * 8];
        }
        #pragma unroll
        for (int ni = 0; ni < 4; ++ni) {
            int n = warpN * 64 + ni * 16 + l15;
            bfr[ni] = *(const short8*)&Bs[n * BK + (quad ^ ((n >> 1) & 3)) * 8];
        }
        #pragma unroll
        for (int mi = 0; mi < 4; ++mi)
            #pragma unroll
            for (int ni = 0; ni < 4; ++ni)
                acc[mi][ni] = __builtin_amdgcn_mfma_f32_16x16x32_bf16(af[mi], bfr[ni], acc[mi][ni], 0, 0, 0);
        __syncthreads();
    }

    const float* __restrict__ sc = (blockIdx.y == 0) ? inv_out : inv_in;
    // C/D layout: col = lane&15 (n), row = quad*4 + reg (m)
    #pragma unroll
    for (int mi = 0; mi < 4; ++mi) {
        #pragma unroll
        for (int reg = 0; reg < 4; ++reg) {
            int gm = bm + warpM * 64 + mi * 16 + quad * 4 + reg;
            if (gm < N) {
                float s = sc[gm];
                #pragma unroll
                for (int ni = 0; ni < 4; ++ni) {
                    int gn = bn + warpN * 64 + ni * 16 + l15;
                    zb[(size_t)gm * D_IN + gn] = f2bf(acc[mi][ni][reg] * s);
                }
            }
        }
    }
}

// ---------------- gather: one wave per node (single dir per launch) ----
// Split into fwd/bwd LAUNCHES: hard phase separation for L2, and each half
// (~65 us) frees top-5 profiler slots so mid-tier kernels become visible.
// Quad decomposition: 4 groups of 16 lanes process 4 different neighbors
// per VMEM instruction (16 B/lane).

__global__ void gather_kernel(const unsigned short* __restrict__ zb, const int* __restrict__ adj,
                              const int* __restrict__ offs, const int* __restrict__ cnt,
                              const float* __restrict__ inv_in, const float* __restrict__ inv_out,
                              const float* __restrict__ bias,
                              float* __restrict__ out, int N, int slotBase, int nSlots) {
    const int wave = threadIdx.x >> 6;
    const int lane = threadIdx.x & 63;
    const int li = blockIdx.x * 4 + wave;
    if (li >= nSlots) return;
    const int slot = slotBase + li;
    const int dir = (slot >= N) ? 1 : 0;
    const int node = slot - dir * N;
    const int beg = offs[slot];
    const int deg = cnt[slot];
    const int end = beg + deg;
    const int g4 = lane >> 4;                  // quad group 0..3
    const int l15 = lane & 15;
    const int chu = dir * D_HALF + 8 * l15;    // ushort offset of this lane's 8 channels
    const int pa = g4 << 2;                    // bpermute base addr for this group

    float a0 = 0.f, a1 = 0.f, a2 = 0.f, a3 = 0.f;
    float a4 = 0.f, a5 = 0.f, a6 = 0.f, a7 = 0.f;

    for (int base = beg; base < end; base += 64) {
        int len = end - base; if (len > 64) len = 64;
        int nb = (lane < len) ? adj[base + lane] : node;
        #pragma unroll 8
        for (int j0 = 0; j0 < len; j0 += 4) {
            int nsel = __builtin_amdgcn_ds_bpermute((j0 << 2) + pa, nb);
            float m = (j0 + g4 < len) ? 1.0f : 0.0f;
            const uint4 u = *(const uint4*)&zb[(size_t)nsel * D_IN + chu];
            a0 = fmaf(m, bflo(u.x), a0); a1 = fmaf(m, bfhi(u.x), a1);
            a2 = fmaf(m, bflo(u.y), a2); a3 = fmaf(m, bfhi(u.y), a3);
            a4 = fmaf(m, bflo(u.z), a4); a5 = fmaf(m, bfhi(u.z), a5);
            a6 = fmaf(m, bflo(u.w), a6); a7 = fmaf(m, bfhi(u.w), a7);
        }
    }

    // reduce across the 4 quad groups (lanes l, l+16, l+32, l+48 share channels)
    a0 += __shfl_xor(a0, 16); a0 += __shfl_xor(a0, 32);
    a1 += __shfl_xor(a1, 16); a1 += __shfl_xor(a1, 32);
    a2 += __shfl_xor(a2, 16); a2 += __shfl_xor(a2, 32);
    a3 += __shfl_xor(a3, 16); a3 += __shfl_xor(a3, 32);
    a4 += __shfl_xor(a4, 16); a4 += __shfl_xor(a4, 32);
    a5 += __shfl_xor(a5, 16); a5 += __shfl_xor(a5, 32);
    a6 += __shfl_xor(a6, 16); a6 += __shfl_xor(a6, 32);
    a7 += __shfl_xor(a7, 16); a7 += __shfl_xor(a7, 32);

    if (g4 == 0) {
        // self row (pre-scaled like every other row), added exactly once
        const uint4 us = *(const uint4*)&zb[(size_t)node * D_IN + chu];
        a0 += bflo(us.x); a1 += bfhi(us.x);
        a2 += bflo(us.y); a3 += bfhi(us.y);
        a4 += bflo(us.z); a5 += bfhi(us.z);
        a6 += bflo(us.w); a7 += bfhi(us.w);

        const float scale = dir ? inv_out[node] : inv_in[node];
        const float4 bv0 = *(const float4*)&bias[chu];
        const float4 bv1 = *(const float4*)&bias[chu + 4];
        size_t oi = (size_t)node * D_IN + chu;
        float4 o0 = { bv0.x + scale * a0, bv0.y + scale * a1,
                      bv0.z + scale * a2, bv0.w + scale * a3 };
        float4 o1 = { bv1.x + scale * a4, bv1.y + scale * a5,
                      bv1.z + scale * a6, bv1.w + scale * a7 };
        *(float4*)&out[oi] = o0;
        *(float4*)&out[oi + 4] = o1;
    }
}

// ---------------- launch ----------------

extern "C" void kernel_launch(void* const* d_in, const int* in_sizes, int n_in,
                              void* d_out, int out_size, void* d_ws, size_t ws_size,
                              hipStream_t stream) {
    const float* x    = (const float*)d_in[0];
    const int*   ei   = (const int*)d_in[1];
    const float* Wf   = (const float*)d_in[2];
    const float* Wb   = (const float*)d_in[3];
    const float* bias = (const float*)d_in[4];
    float* out = (float*)d_out;

    const int N = in_sizes[0] / D_IN;
    const int E = in_sizes[1] / 2;
    const int* col = ei;
    const int* rowp = ei + E;

    // workspace
    char* ws = (char*)d_ws;
    unsigned short* xb = (unsigned short*)ws;   ws += (size_t)N * D_IN * sizeof(short);
    unsigned short* zb = (unsigned short*)ws;   ws += (size_t)N * D_IN * sizeof(short);
    unsigned short* wcat = (unsigned short*)ws; ws += (size_t)2 * D_HALF * D_IN * sizeof(short);
    int* cnt = (int*)ws;            ws += (size_t)2 * N * sizeof(int);
    int* offs = (int*)ws;           ws += (size_t)2 * N * sizeof(int);
    float* inv_in = (float*)ws;     ws += (size_t)N * sizeof(float);
    float* inv_out = (float*)ws;    ws += (size_t)N * sizeof(float);
    int* adj = (int*)ws;            ws += (size_t)2 * E * sizeof(int);
    int* gcnt = (int*)ws;           ws += NBK_MAX * sizeof(int);

    // staging aliases zb: zb (51.2 MB) is first written by the GEMM, which
    // runs after bsort_kernel in stream order; staging needs 391*CAP*4 = 19.2 MB.
    unsigned* staging = (unsigned*)zb;

    const int M = 2 * N;
    const int nbuck = (M + 511) >> S_SH;
    const int nP1 = (E + EPB - 1) / EPB;
    const int n4 = N * D_IN / 4;
    const int w4 = (2 * D_HALF * D_IN) / 4;
    const int nCast = (n4 + w4 + 255) / 256;

    hipMemsetAsync(gcnt, 0, NBK_MAX * sizeof(int), stream);
    p1_cast_kernel<<<nP1 + nCast, 256, 0, stream>>>(col, rowp, gcnt, staging, N, E, nP1,
                                                    x, Wf, Wb, xb, wcat, n4);
    bsort_kernel<<<nbuck, 256, 0, stream>>>(staging, gcnt, cnt, offs, inv_in, inv_out, adj, N, M);

    gemm_mfma_kernel<<<dim3((N + BM - 1) / BM, D_IN / BN), 256, 0, stream>>>(xb, wcat, inv_in, inv_out, zb, N);

    gather_kernel<<<(N + 3) / 4, 256, 0, stream>>>(zb, adj, offs, cnt, inv_in, inv_out, bias, out, N, 0, N);
    gather_kernel<<<(N + 3) / 4, 256, 0, stream>>>(zb, adj, offs, cnt, inv_in, inv_out, bias, out, N, N, N);
}

// Round 11
// 377.731 us; speedup vs baseline: 1.0712x; 1.0712x over previous
//
#include <hip/hip_runtime.h>

#define D_IN 256
#define D_HALF 128

typedef __attribute__((ext_vector_type(8))) short short8;
typedef __attribute__((ext_vector_type(4))) float float4v;

__device__ __forceinline__ unsigned short f2bf(float f) {
    union { float f; unsigned u; } v; v.f = f;
    unsigned r = v.u + 0x7FFF + ((v.u >> 16) & 1);   // RNE
    return (unsigned short)(r >> 16);
}
__device__ __forceinline__ float bflo(unsigned u) { union { unsigned u; float f; } v; v.u = u << 16; return v.f; }
__device__ __forceinline__ float bfhi(unsigned u) { union { unsigned u; float f; } v; v.u = u & 0xffff0000u; return v.f; }

__device__ __forceinline__ void async16(const void* g, void* l) {
    __builtin_amdgcn_global_load_lds(
        (const __attribute__((address_space(1))) unsigned int*)g,
        (__attribute__((address_space(3))) unsigned int*)l, 16, 0, 0);
}

// ---------------- CSR build ----------------
// Fixed-capacity bucket sort. Bucket = 256 consecutive csr slots (S_SH=8):
// doubles bsort block count (782) and shrinks bsort LDS to ~25 KB so ~3
// blocks/CU stay resident (was 1.5 at S_SH=9, the occupancy bottleneck).
// Item packed in u32: (slot_local << 23) | nbr   (needs N < 2^23).

#define S_SH 8               // 256 csr slots per bucket
#define NBK_MAX 1024         // max buckets (M <= 1024*256 = 262144)
#define CAP 4608             // items per bucket (mean 4092, sigma ~64 -> +8s)
#define EPB 4096             // edges per p1 block (16 per thread @ 256 thr)

// Fat kernel: blocks [0, nP1) run the p1 partition pass (direct scatter,
// 8 KB LDS -> high occupancy for BOTH branches; R10 showed the 56 KB LDS
// reorder variant collapsed occupancy to 2 blocks/CU and cost net time);
// blocks [nP1, ...) run the independent x/W bf16 cast and fill idle CUs.
__global__ void p1_cast_kernel(const int* __restrict__ col, const int* __restrict__ row,
                               int* __restrict__ gcnt, unsigned* __restrict__ staging,
                               int N, int E, int nP1,
                               const float* __restrict__ x, const float* __restrict__ Wf,
                               const float* __restrict__ Wb, unsigned short* __restrict__ xb,
                               unsigned short* __restrict__ wcat, int n4) {
    __shared__ int hist[NBK_MAX];
    __shared__ int base_[NBK_MAX];
    const int tid = threadIdx.x;

    if (blockIdx.x >= nP1) {
        // ---- cast branch (no barriers) ----
        int i = (blockIdx.x - nP1) * 256 + tid;
        const int w4 = (2 * D_HALF * D_IN) / 4;
        if (i < n4) {
            float4 v = ((const float4*)x)[i];
            ushort4 o = { f2bf(v.x), f2bf(v.y), f2bf(v.z), f2bf(v.w) };
            ((ushort4*)xb)[i] = o;
        } else if (i < n4 + w4) {
            int j = i - n4;
            int elem = j * 4;
            const float* src = (elem < D_HALF * D_IN) ? (Wf + elem) : (Wb + (elem - D_HALF * D_IN));
            float4 v = *(const float4*)src;
            ushort4 o = { f2bf(v.x), f2bf(v.y), f2bf(v.z), f2bf(v.w) };
            ((ushort4*)wcat)[j] = o;
        }
        return;
    }

    // ---- p1 branch: stream edges once (held in registers); pass-1 LDS
    // atomic return value IS the within-block rank, so no second pass. ----
    #pragma unroll
    for (int b = 0; b < NBK_MAX / 256; ++b) hist[b * 256 + tid] = 0;
    __syncthreads();

    int ce[16], re[16], rf_[16], rb_[16];
    const int e0 = blockIdx.x * EPB;
    #pragma unroll
    for (int j = 0; j < 16; ++j) {
        int e = e0 + j * 256 + tid;
        if (e < E) {
            ce[j] = col[e];
            re[j] = row[e];
            rf_[j] = atomicAdd(&hist[ce[j] >> S_SH], 1);
            rb_[j] = atomicAdd(&hist[(N + re[j]) >> S_SH], 1);
        } else {
            ce[j] = -1; re[j] = 0; rf_[j] = 0; rb_[j] = 0;
        }
    }
    __syncthreads();

    #pragma unroll
    for (int b = 0; b < NBK_MAX / 256; ++b) {
        int idx = b * 256 + tid;
        int c = hist[idx];
        if (c) base_[idx] = idx * CAP + atomicAdd(&gcnt[idx], c);
    }
    __syncthreads();

    #pragma unroll
    for (int j = 0; j < 16; ++j) {
        if (ce[j] >= 0) {
            int c = ce[j], r = re[j];
            staging[(size_t)base_[c >> S_SH] + rf_[j]] =
                ((unsigned)(c & 255) << 23) | (unsigned)r;
            int sb = N + r;
            staging[(size_t)base_[sb >> S_SH] + rb_[j]] =
                ((unsigned)(sb & 255) << 23) | (unsigned)c;
        }
    }
}

// One block per bucket, one csr SLOT per thread (256 slots = 256 threads).
// Inlined: (a) scan of gcnt[1024] (4/thread) -> this bucket's global base;
// (b) per-slot hist + scan -> cnt/offs AND inv_in/inv_out written directly;
// (c) rank+scatter into LDS, coalesced contiguous adj write.
// LDS ~25 KB -> ~3 resident blocks/CU (vs 1.5 at S_SH=9).
__global__ void bsort_kernel(const unsigned* __restrict__ staging, const int* __restrict__ gcnt,
                             int* __restrict__ cnt, int* __restrict__ offs,
                             float* __restrict__ inv_in, float* __restrict__ inv_out,
                             int* __restrict__ adj, int N, int M) {
    __shared__ int lcnt[256];
    __shared__ int s[256];
    __shared__ int lbuf[CAP];
    __shared__ int bc[2];            // [0]=base, [1]=count broadcast
    const int tid = threadIdx.x;
    const int b = blockIdx.x;
    const int s0 = b << S_SH;

    // (a) bucket-base scan: prefix over gcnt[0..1024), 4 entries per thread
    int g0 = gcnt[4 * tid], g1 = gcnt[4 * tid + 1];
    int g2 = gcnt[4 * tid + 2], g3 = gcnt[4 * tid + 3];
    int loc = g0 + g1 + g2 + g3;
    s[tid] = loc;
    __syncthreads();
    for (int d = 1; d < 256; d <<= 1) {
        int t = (tid >= d) ? s[tid - d] : 0;
        __syncthreads();
        s[tid] += t;
        __syncthreads();
    }
    if (tid == (b >> 2)) {
        int e = s[tid] - loc;                    // prefix before bucket 4*tid
        int r = b & 3;
        if (r > 0) e += g0;
        if (r > 1) e += g1;
        if (r > 2) e += g2;
        bc[0] = e;
        bc[1] = (r == 0) ? g0 : (r == 1) ? g1 : (r == 2) ? g2 : g3;
    }
    lcnt[tid] = 0;
    __syncthreads();

    const int base = bc[0];
    const int count = bc[1];
    const unsigned* __restrict__ st = staging + (size_t)b * CAP;

    // (b) per-slot histogram
    for (int i = tid; i < count; i += 256)
        atomicAdd(&lcnt[st[i] >> 23], 1);
    __syncthreads();

    int v = lcnt[tid];
    s[tid] = v;
    __syncthreads();
    for (int d = 1; d < 256; d <<= 1) {
        int t = (tid >= d) ? s[tid - d] : 0;
        __syncthreads();
        s[tid] += t;
        __syncthreads();
    }
    int excl = s[tid] - v;

    int gs = s0 + tid;
    if (gs < M) {
        cnt[gs] = v;  offs[gs] = base + excl;
        float iv = rsqrtf((float)(v + 1));
        if (gs < N) inv_in[gs] = iv;
        else        inv_out[gs - N] = iv;
    }

    // reuse lcnt as running positions
    lcnt[tid] = excl;
    __syncthreads();

    // (c) rank + LDS scatter, then coalesced write
    for (int i = tid; i < count; i += 256) {
        unsigned it = st[i];
        int sl = it >> 23;
        int p = atomicAdd(&lcnt[sl], 1);
        lbuf[p] = (int)(it & 0x7fffffu);
    }
    __syncthreads();
    for (int i = tid; i < count; i += 256)
        adj[base + i] = lbuf[i];
}

// ---------------- bf16 MFMA GEMM with pre-scaled epilogue ----------------
// zb[m][n] = f2bf( (sum_k xb[m][k]*wcat[n][k]) * s[m] )
// s[m] = inv_out[m] for forward half (blockIdx.y==0), inv_in[m] for backward.

#define BM 128
#define BN 128
#define BK 32

__global__ void gemm_mfma_kernel(const unsigned short* __restrict__ xb,
                                 const unsigned short* __restrict__ wcat,
                                 const float* __restrict__ inv_in,
                                 const float* __restrict__ inv_out,
                                 unsigned short* __restrict__ zb, int N) {
    __shared__ __align__(16) unsigned short As[BM * BK];
    __shared__ __align__(16) unsigned short Bs[BN * BK];
    const int tid = threadIdx.x;
    const int wave = tid >> 6;
    const int lane = tid & 63;
    const int bm = blockIdx.x * BM;
    const int bn = blockIdx.y * BN;
    const int warpM = wave >> 1;   // 0..1
    const int warpN = wave & 1;    // 0..1
    const int l15 = lane & 15;
    const int quad = lane >> 4;

    float4v acc[4][4];
    #pragma unroll
    for (int i = 0; i < 4; ++i)
        #pragma unroll
        for (int j = 0; j < 4; ++j)
            acc[i][j] = (float4v){0.f, 0.f, 0.f, 0.f};

    for (int kt = 0; kt < D_IN / BK; ++kt) {
        #pragma unroll
        for (int iss = 0; iss < 2; ++iss) {
            const int pbase = iss * 256 + wave * 64;
            const int p = pbase + lane;
            const int m = p >> 2;
            const int g = (p & 3) ^ ((m >> 1) & 3);
            int gm = bm + m; if (gm >= N) gm = N - 1;
            async16(xb + (size_t)gm * D_IN + kt * BK + g * 8, &As[pbase * 8]);
            async16(wcat + (size_t)(bn + m) * D_IN + kt * BK + g * 8, &Bs[pbase * 8]);
        }
        __syncthreads();

        short8 af[4], bfr[4];
        #pragma unroll
        for (int mi = 0; mi < 4; ++mi) {
            int m = warpM * 64 + mi * 16 + l15;
            af[mi] = *(const short8*)&As[m * BK + (quad ^ ((m >> 1) & 3)) * 8];
        }
        #pragma unroll
        for (int ni = 0; ni < 4; ++ni) {
            int n = warpN * 64 + ni * 16 + l15;
            bfr[ni] = *(const short8*)&Bs[n * BK + (quad ^ ((n >> 1) & 3)) * 8];
        }
        #pragma unroll
        for (int mi = 0; mi < 4; ++mi)
            #pragma unroll
            for (int ni = 0; ni < 4; ++ni)
                acc[mi][ni] = __builtin_amdgcn_mfma_f32_16x16x32_bf16(af[mi], bfr[ni], acc[mi][ni], 0, 0, 0);
        __syncthreads();
    }

    const float* __restrict__ sc = (blockIdx.y == 0) ? inv_out : inv_in;
    // C/D layout: col = lane&15 (n), row = quad*4 + reg (m)
    #pragma unroll
    for (int mi = 0; mi < 4; ++mi) {
        #pragma unroll
        for (int reg = 0; reg < 4; ++reg) {
            int gm = bm + warpM * 64 + mi * 16 + quad * 4 + reg;
            if (gm < N) {
                float s = sc[gm];
                #pragma unroll
                for (int ni = 0; ni < 4; ++ni) {
                    int gn = bn + warpN * 64 + ni * 16 + l15;
                    zb[(size_t)gm * D_IN + gn] = f2bf(acc[mi][ni][reg] * s);
                }
            }
        }
    }
}

// ---------------- gather: one wave per (node, dir), pre-scaled bf16 z ----
// PHASE-ORDERED (dir = slot >= N) + quad decomposition: 4 groups of 16
// lanes process 4 different neighbors per VMEM instruction (16 B/lane).

__global__ void gather_kernel(const unsigned short* __restrict__ zb, const int* __restrict__ adj,
                              const int* __restrict__ offs, const int* __restrict__ cnt,
                              const float* __restrict__ inv_in, const float* __restrict__ inv_out,
                              const float* __restrict__ bias,
                              float* __restrict__ out, int N) {
    const int wave = threadIdx.x >> 6;
    const int lane = threadIdx.x & 63;
    const int slot = blockIdx.x * 4 + wave;
    if (slot >= 2 * N) return;
    const int dir = (slot >= N) ? 1 : 0;
    const int node = slot - dir * N;
    const int beg = offs[slot];
    const int deg = cnt[slot];
    const int end = beg + deg;
    const int g4 = lane >> 4;                  // quad group 0..3
    const int l15 = lane & 15;
    const int chu = dir * D_HALF + 8 * l15;    // ushort offset of this lane's 8 channels
    const int pa = g4 << 2;                    // bpermute base addr for this group

    float a0 = 0.f, a1 = 0.f, a2 = 0.f, a3 = 0.f;
    float a4 = 0.f, a5 = 0.f, a6 = 0.f, a7 = 0.f;

    for (int base = beg; base < end; base += 64) {
        int len = end - base; if (len > 64) len = 64;
        int nb = (lane < len) ? adj[base + lane] : node;
        #pragma unroll 8
        for (int j0 = 0; j0 < len; j0 += 4) {
            int nsel = __builtin_amdgcn_ds_bpermute((j0 << 2) + pa, nb);
            float m = (j0 + g4 < len) ? 1.0f : 0.0f;
            const uint4 u = *(const uint4*)&zb[(size_t)nsel * D_IN + chu];
            a0 = fmaf(m, bflo(u.x), a0); a1 = fmaf(m, bfhi(u.x), a1);
            a2 = fmaf(m, bflo(u.y), a2); a3 = fmaf(m, bfhi(u.y), a3);
            a4 = fmaf(m, bflo(u.z), a4); a5 = fmaf(m, bfhi(u.z), a5);
            a6 = fmaf(m, bflo(u.w), a6); a7 = fmaf(m, bfhi(u.w), a7);
        }
    }

    // reduce across the 4 quad groups (lanes l, l+16, l+32, l+48 share channels)
    a0 += __shfl_xor(a0, 16); a0 += __shfl_xor(a0, 32);
    a1 += __shfl_xor(a1, 16); a1 += __shfl_xor(a1, 32);
    a2 += __shfl_xor(a2, 16); a2 += __shfl_xor(a2, 32);
    a3 += __shfl_xor(a3, 16); a3 += __shfl_xor(a3, 32);
    a4 += __shfl_xor(a4, 16); a4 += __shfl_xor(a4, 32);
    a5 += __shfl_xor(a5, 16); a5 += __shfl_xor(a5, 32);
    a6 += __shfl_xor(a6, 16); a6 += __shfl_xor(a6, 32);
    a7 += __shfl_xor(a7, 16); a7 += __shfl_xor(a7, 32);

    if (g4 == 0) {
        // self row (pre-scaled like every other row), added exactly once
        const uint4 us = *(const uint4*)&zb[(size_t)node * D_IN + chu];
        a0 += bflo(us.x); a1 += bfhi(us.x);
        a2 += bflo(us.y); a3 += bfhi(us.y);
        a4 += bflo(us.z); a5 += bfhi(us.z);
        a6 += bflo(us.w); a7 += bfhi(us.w);

        const float scale = dir ? inv_out[node] : inv_in[node];
        const float4 bv0 = *(const float4*)&bias[chu];
        const float4 bv1 = *(const float4*)&bias[chu + 4];
        size_t oi = (size_t)node * D_IN + chu;
        float4 o0 = { bv0.x + scale * a0, bv0.y + scale * a1,
                      bv0.z + scale * a2, bv0.w + scale * a3 };
        float4 o1 = { bv1.x + scale * a4, bv1.y + scale * a5,
                      bv1.z + scale * a6, bv1.w + scale * a7 };
        *(float4*)&out[oi] = o0;
        *(float4*)&out[oi + 4] = o1;
    }
}

// ---------------- launch ----------------

extern "C" void kernel_launch(void* const* d_in, const int* in_sizes, int n_in,
                              void* d_out, int out_size, void* d_ws, size_t ws_size,
                              hipStream_t stream) {
    const float* x    = (const float*)d_in[0];
    const int*   ei   = (const int*)d_in[1];
    const float* Wf   = (const float*)d_in[2];
    const float* Wb   = (const float*)d_in[3];
    const float* bias = (const float*)d_in[4];
    float* out = (float*)d_out;

    const int N = in_sizes[0] / D_IN;
    const int E = in_sizes[1] / 2;
    const int* col = ei;
    const int* rowp = ei + E;

    // workspace
    char* ws = (char*)d_ws;
    unsigned short* xb = (unsigned short*)ws;   ws += (size_t)N * D_IN * sizeof(short);
    unsigned short* zb = (unsigned short*)ws;   ws += (size_t)N * D_IN * sizeof(short);
    unsigned short* wcat = (unsigned short*)ws; ws += (size_t)2 * D_HALF * D_IN * sizeof(short);
    int* cnt = (int*)ws;            ws += (size_t)2 * N * sizeof(int);
    int* offs = (int*)ws;           ws += (size_t)2 * N * sizeof(int);
    float* inv_in = (float*)ws;     ws += (size_t)N * sizeof(float);
    float* inv_out = (float*)ws;    ws += (size_t)N * sizeof(float);
    int* adj = (int*)ws;            ws += (size_t)2 * E * sizeof(int);
    int* gcnt = (int*)ws;           ws += NBK_MAX * sizeof(int);

    // staging aliases zb: zb (51.2 MB) is first written by the GEMM, which
    // runs after bsort_kernel in stream order; staging needs 1024*CAP*4 = 18.9 MB.
    unsigned* staging = (unsigned*)zb;

    const int M = 2 * N;
    const int nbuck = (M + 255) >> S_SH;
    const int nP1 = (E + EPB - 1) / EPB;
    const int n4 = N * D_IN / 4;
    const int w4 = (2 * D_HALF * D_IN) / 4;
    const int nCast = (n4 + w4 + 255) / 256;

    hipMemsetAsync(gcnt, 0, NBK_MAX * sizeof(int), stream);
    p1_cast_kernel<<<nP1 + nCast, 256, 0, stream>>>(col, rowp, gcnt, staging, N, E, nP1,
                                                    x, Wf, Wb, xb, wcat, n4);
    bsort_kernel<<<nbuck, 256, 0, stream>>>(staging, gcnt, cnt, offs, inv_in, inv_out, adj, N, M);

    gemm_mfma_kernel<<<dim3((N + BM - 1) / BM, D_IN / BN), 256, 0, stream>>>(xb, wcat, inv_in, inv_out, zb, N);

    gather_kernel<<<(2 * N + 3) / 4, 256, 0, stream>>>(zb, adj, offs, cnt, inv_in, inv_out, bias, out, N);
}